// Round 3
// baseline (1140.180 us; speedup 1.0000x reference)
//
#include <hip/hip_runtime.h>
#include <math.h>

// ---------------- model dims ----------------
#define NB    8      // batch
#define E     256    // embed
#define LTOK  256    // tokens
#define DI    512    // inner dim
#define DS    16     // state dim
#define DTR   16     // dt rank
#define NC    16     // scan chunks
#define CL    16     // chunk length (LTOK/NC)

__device__ __forceinline__ float gelu_f(float x) {
    return 0.5f * x * (1.0f + erff(x * 0.70710678118654752440f));
}
__device__ __forceinline__ float silu_f(float x) {
    return x / (1.0f + expf(-x));
}
__device__ __forceinline__ float softplus_f(float x) {
    return fmaxf(x, 0.0f) + log1pf(expf(-fabsf(x)));
}

// block-wide sum over 256 threads (4 waves). red must be __shared__ float[4].
__device__ __forceinline__ float block_sum256(float x, float* red) {
#pragma unroll
    for (int off = 32; off > 0; off >>= 1) x += __shfl_down(x, off, 64);
    __syncthreads();
    if ((threadIdx.x & 63) == 0) red[threadIdx.x >> 6] = x;
    __syncthreads();
    return red[0] + red[1] + red[2] + red[3];
}

// ---------------- time embedding ----------------
__global__ void time_emb_kernel(const int* __restrict__ t,
                                const float* __restrict__ w1, const float* __restrict__ b1,
                                const float* __restrict__ w2, const float* __restrict__ b2,
                                float* __restrict__ temb) {
    int b = blockIdx.x, e = threadIdx.x;
    __shared__ float hid[E];
    float tf = (float)t[b];
    hid[e] = gelu_f(tf * w1[e] + b1[e]);
    __syncthreads();
    float acc = b2[e];
    for (int k = 0; k < E; ++k) acc = fmaf(hid[k], w2[k * E + e], acc);
    temb[b * E + e] = acc;
}

// ---------------- patch gather: x -> P (2048 x 512) row-major ----------------
__global__ void gather_patches(const float* __restrict__ x, float* __restrict__ P) {
    int idx = blockIdx.x * 256 + threadIdx.x;          // < 262144
    int k4 = idx & 127, m = idx >> 7;
    int b = m >> 8, l = m & 255, hh = l >> 4, ww = l & 15;
    int k = k4 * 4;
    int c = k >> 8, pq = k & 255, p = pq >> 4, q = pq & 15;
    float4 v = *(const float4*)&x[(((size_t)(b * 2 + c) * 256) + hh * 16 + p) * 256 + ww * 16 + q];
    *(float4*)&P[(size_t)m * 512 + k] = v;
}

// ---------------- generic fp32 GEMM (NT): C[m,n] = sum_k A[m,k]*Bw[n,k] ----------------
// BM=64, BN=64, BK=16, TM=4, TN=4, 256 threads. blockIdx.z = K-split slice.
__global__ __launch_bounds__(256, 4) void gemm_nt(
    const float* __restrict__ A, int lda,
    const float* __restrict__ Bw, int ldb,
    float* __restrict__ C, int ldc, int K, int zstride) {
    const int tid = threadIdx.x;
    const int n0 = blockIdx.x * 64, m0 = blockIdx.y * 64;
    const int kbase = blockIdx.z * K;
    float* Cz = C + (size_t)blockIdx.z * zstride;
    __shared__ float As[16][68];
    __shared__ float Bs[16][68];
    const int tx = tid & 15, ty = tid >> 4;
    const int smm = tid >> 2, sk4 = tid & 3;
    float acc[4][4] = {};
    for (int k0 = 0; k0 < K; k0 += 16) {
        // stage A (transpose, float4 global; 2-way LDS bank aliasing = free)
        {
            float4 v = *(const float4*)&A[(size_t)(m0 + smm) * lda + kbase + k0 + sk4 * 4];
            As[sk4 * 4 + 0][smm] = v.x;
            As[sk4 * 4 + 1][smm] = v.y;
            As[sk4 * 4 + 2][smm] = v.z;
            As[sk4 * 4 + 3][smm] = v.w;
        }
        // stage B (transpose)
        {
            float4 v = *(const float4*)&Bw[(size_t)(n0 + smm) * ldb + kbase + k0 + sk4 * 4];
            Bs[sk4 * 4 + 0][smm] = v.x;
            Bs[sk4 * 4 + 1][smm] = v.y;
            Bs[sk4 * 4 + 2][smm] = v.z;
            Bs[sk4 * 4 + 3][smm] = v.w;
        }
        __syncthreads();
#pragma unroll
        for (int kk = 0; kk < 16; ++kk) {
            float4 av = *(const float4*)&As[kk][ty * 4];
            float4 bv = *(const float4*)&Bs[kk][tx * 4];
            float a[4] = {av.x, av.y, av.z, av.w};
            float b[4] = {bv.x, bv.y, bv.z, bv.w};
#pragma unroll
            for (int i = 0; i < 4; ++i)
#pragma unroll
                for (int j = 0; j < 4; ++j) acc[i][j] = fmaf(a[i], b[j], acc[i][j]);
        }
        __syncthreads();
    }
#pragma unroll
    for (int i = 0; i < 4; ++i) {
        int m = m0 + ty * 4 + i;
        *(float4*)&Cz[(size_t)m * ldc + n0 + tx * 4] =
            make_float4(acc[i][0], acc[i][1], acc[i][2], acc[i][3]);
    }
}

// ---------------- LN (patch variant): v = part0+part1+pb+pos+temb ----------------
__global__ __launch_bounds__(256) void ln_patch(
    const float* __restrict__ part, const float* __restrict__ pb,
    const float* __restrict__ pos, const float* __restrict__ temb,
    const float* __restrict__ g, const float* __restrict__ bta,
    float* __restrict__ h, float* __restrict__ hn) {
    __shared__ float red[4];
    int m = blockIdx.x, e = threadIdx.x;
    int b = m >> 8, l = m & 255;
    size_t o = (size_t)m * 256 + e;
    float v = part[o] + part[524288 + o] + pb[e] + pos[l * 256 + e] + temb[b * 256 + e];
    h[o] = v;
    float mean = block_sum256(v, red) * (1.0f / 256.0f);
    float dv = v - mean;
    float var = block_sum256(dv * dv, red) * (1.0f / 256.0f);
    float rstd = rsqrtf(var + 1e-5f);
    hn[o] = dv * rstd * g[e] + bta[e];
}

// ---------------- LN (residual variant): v = part0+part1+h ----------------
__global__ __launch_bounds__(256) void ln_residual(
    const float* __restrict__ part,
    const float* __restrict__ g, const float* __restrict__ bta,
    float* __restrict__ h, float* __restrict__ hn, int do_ln) {
    __shared__ float red[4];
    int m = blockIdx.x, e = threadIdx.x;
    size_t o = (size_t)m * 256 + e;
    float v = part[o] + part[524288 + o] + h[o];
    h[o] = v;
    if (!do_ln) return;
    float mean = block_sum256(v, red) * (1.0f / 256.0f);
    float dv = v - mean;
    float var = block_sum256(dv * dv, red) * (1.0f / 256.0f);
    float rstd = rsqrtf(var + 1e-5f);
    hn[o] = dv * rstd * g[e] + bta[e];
}

// ---------------- x_proj GEMM with fused conv+silu A-staging ----------------
// grid (1, 64, 4), 256 threads; per-slice K = 128
__global__ __launch_bounds__(256, 4) void xproj_gemm(
    const float* __restrict__ xz, const float* __restrict__ xpw,
    const float* __restrict__ cw, const float* __restrict__ cb,
    float* __restrict__ partx) {
    const int tid = threadIdx.x;
    const int m0 = blockIdx.y * 32;
    const int kb = blockIdx.z * 128;
    __shared__ float As[16][36];
    __shared__ float Bs[16][52];
    const int tx = tid & 15, ty = tid >> 4;
    float acc[2][3] = {};
    for (int k0 = 0; k0 < 128; k0 += 16) {
#pragma unroll
        for (int idx = tid; idx < 512; idx += 256) {
            int mm = idx >> 4, kk = idx & 15;
            int d = kb + k0 + kk;
            int m = m0 + mm;
            int l = m & 255;
            float4 w4 = *(const float4*)&cw[d * 4];
            float a = cb[d];
            const float* col = xz + (size_t)m * 1024 + d;
            if (l >= 3) {
                a = fmaf(col[-3072], w4.x, a);
                a = fmaf(col[-2048], w4.y, a);
                a = fmaf(col[-1024], w4.z, a);
                a = fmaf(col[0],     w4.w, a);
            } else {
                if (l >= 2) a = fmaf(col[-2048], w4.y, a);
                if (l >= 1) a = fmaf(col[-1024], w4.z, a);
                a = fmaf(col[0], w4.w, a);
            }
            As[kk][mm] = silu_f(a);
        }
#pragma unroll
        for (int idx = tid; idx < 768; idx += 256) {
            int nn = idx >> 4, kk = idx & 15;
            Bs[kk][nn] = xpw[(size_t)nn * 512 + kb + k0 + kk];
        }
        __syncthreads();
#pragma unroll
        for (int kk = 0; kk < 16; ++kk) {
            float a0 = As[kk][ty * 2 + 0];
            float a1 = As[kk][ty * 2 + 1];
            float b0 = Bs[kk][tx * 3 + 0];
            float b1 = Bs[kk][tx * 3 + 1];
            float b2 = Bs[kk][tx * 3 + 2];
            acc[0][0] = fmaf(a0, b0, acc[0][0]);
            acc[0][1] = fmaf(a0, b1, acc[0][1]);
            acc[0][2] = fmaf(a0, b2, acc[0][2]);
            acc[1][0] = fmaf(a1, b0, acc[1][0]);
            acc[1][1] = fmaf(a1, b1, acc[1][1]);
            acc[1][2] = fmaf(a1, b2, acc[1][2]);
        }
        __syncthreads();
    }
    size_t zb = (size_t)blockIdx.z * 98304;
#pragma unroll
    for (int i = 0; i < 2; ++i) {
        int m = m0 + ty * 2 + i;
#pragma unroll
        for (int j = 0; j < 3; ++j)
            partx[zb + (size_t)m * 48 + tx * 3 + j] = acc[i][j];
    }
}

// ---------------- scan phase 1: local chunk scans ----------------
// grid (NC, NB, 2), 256 threads; d = z*256+tid
__global__ __launch_bounds__(256, 4) void scan_phase1(
    const float* __restrict__ partx, const float* __restrict__ xz,
    const float* __restrict__ cw, const float* __restrict__ cb,
    const float* __restrict__ dtw, const float* __restrict__ dtb,
    const float* __restrict__ alog,
    float* __restrict__ hpart, float* __restrict__ pprod) {
    int c = blockIdx.x, b = blockIdx.y;
    int d = blockIdx.z * 256 + threadIdx.x;
    __shared__ float dbcS[CL][48];
#pragma unroll
    for (int idx = threadIdx.x; idx < CL * 48; idx += 256) {
        int r = idx / 48, col = idx % 48;
        size_t o = (size_t)(b * LTOK + c * CL + r) * 48 + col;
        dbcS[r][col] = partx[o] + partx[98304 + o] + partx[196608 + o] + partx[294912 + o];
    }
    float wv[16], Av[16];
#pragma unroll
    for (int s4 = 0; s4 < 16; s4 += 4) {
        float4 t1 = *(const float4*)(dtw + d * 16 + s4);
        wv[s4] = t1.x; wv[s4 + 1] = t1.y; wv[s4 + 2] = t1.z; wv[s4 + 3] = t1.w;
        float4 t2 = *(const float4*)(alog + d * 16 + s4);
        Av[s4] = -expf(t2.x); Av[s4 + 1] = -expf(t2.y); Av[s4 + 2] = -expf(t2.z); Av[s4 + 3] = -expf(t2.w);
    }
    float bv = dtb[d];
    float4 cwv = *(const float4*)&cw[d * 4];
    float cbv = cb[d];
    const float* colp = xz + ((size_t)(b * LTOK + c * CL)) * 1024 + d;
    float x0 = 0.f, x1 = 0.f, x2 = 0.f;
    if (c > 0) { x0 = colp[-3072]; x1 = colp[-2048]; x2 = colp[-1024]; }
    float h[16] = {}, P[16];
#pragma unroll
    for (int s = 0; s < 16; ++s) P[s] = 1.0f;
    __syncthreads();
    for (int r = 0; r < CL; ++r) {
        float xin = colp[r * 1024];
        float uv = cbv;
        uv = fmaf(x0, cwv.x, uv);
        uv = fmaf(x1, cwv.y, uv);
        uv = fmaf(x2, cwv.z, uv);
        uv = fmaf(xin, cwv.w, uv);
        uv = silu_f(uv);
        x0 = x1; x1 = x2; x2 = xin;
        float pre = bv;
#pragma unroll
        for (int j = 0; j < 16; ++j) pre = fmaf(dbcS[r][j], wv[j], pre);
        float dt = softplus_f(pre);
        float du = dt * uv;
#pragma unroll
        for (int s = 0; s < 16; ++s) {
            float dA = expf(dt * Av[s]);
            h[s] = fmaf(dA, h[s], du * dbcS[r][16 + s]);
            P[s] *= dA;
        }
    }
    size_t base = ((size_t)((b * NC + c) * DI) + d) * 16;
#pragma unroll
    for (int s = 0; s < 16; ++s) { hpart[base + s] = h[s]; pprod[base + s] = P[s]; }
}

// ---------------- scan phase 3: prefix-from-partials + replay, emit y*silu(z) ----------
__global__ __launch_bounds__(256, 4) void scan_phase3(
    const float* __restrict__ partx, const float* __restrict__ xz,
    const float* __restrict__ cw, const float* __restrict__ cb,
    const float* __restrict__ dtw, const float* __restrict__ dtb,
    const float* __restrict__ alog, const float* __restrict__ Dpv,
    const float* __restrict__ hpart, const float* __restrict__ pprod,
    float* __restrict__ yz) {
    int c = blockIdx.x, b = blockIdx.y;
    int d = blockIdx.z * 256 + threadIdx.x;
    __shared__ float dbcS[CL][48];
#pragma unroll
    for (int idx = threadIdx.x; idx < CL * 48; idx += 256) {
        int r = idx / 48, col = idx % 48;
        size_t o = (size_t)(b * LTOK + c * CL + r) * 48 + col;
        dbcS[r][col] = partx[o] + partx[98304 + o] + partx[196608 + o] + partx[294912 + o];
    }
    float wv[16], Av[16];
#pragma unroll
    for (int s4 = 0; s4 < 16; s4 += 4) {
        float4 t1 = *(const float4*)(dtw + d * 16 + s4);
        wv[s4] = t1.x; wv[s4 + 1] = t1.y; wv[s4 + 2] = t1.z; wv[s4 + 3] = t1.w;
        float4 t2 = *(const float4*)(alog + d * 16 + s4);
        Av[s4] = -expf(t2.x); Av[s4 + 1] = -expf(t2.y); Av[s4 + 2] = -expf(t2.z); Av[s4 + 3] = -expf(t2.w);
    }
    float bv = dtb[d];
    float Dv = Dpv[d];
    float4 cwv = *(const float4*)&cw[d * 4];
    float cbv = cb[d];
    // chunk-prefix carry: h = sum_{cc<c} (prod of later P) * hpart(cc)  [inclusive chain]
    float h[16] = {};
    for (int cc = 0; cc < c; ++cc) {
        size_t a = ((size_t)((b * NC + cc) * DI) + d) * 16;
#pragma unroll
        for (int s4 = 0; s4 < 16; s4 += 4) {
            float4 hp = *(const float4*)&hpart[a + s4];
            float4 pp = *(const float4*)&pprod[a + s4];
            h[s4 + 0] = fmaf(pp.x, h[s4 + 0], hp.x);
            h[s4 + 1] = fmaf(pp.y, h[s4 + 1], hp.y);
            h[s4 + 2] = fmaf(pp.z, h[s4 + 2], hp.z);
            h[s4 + 3] = fmaf(pp.w, h[s4 + 3], hp.w);
        }
    }
    const float* colp = xz + ((size_t)(b * LTOK + c * CL)) * 1024 + d;
    const float* zrow = xz + ((size_t)(b * LTOK + c * CL)) * 1024 + 512 + d;
    float* yrow = yz + ((size_t)(b * LTOK + c * CL)) * 512 + d;
    float x0 = 0.f, x1 = 0.f, x2 = 0.f;
    if (c > 0) { x0 = colp[-3072]; x1 = colp[-2048]; x2 = colp[-1024]; }
    __syncthreads();
    for (int r = 0; r < CL; ++r) {
        float xin = colp[r * 1024];
        float uv = cbv;
        uv = fmaf(x0, cwv.x, uv);
        uv = fmaf(x1, cwv.y, uv);
        uv = fmaf(x2, cwv.z, uv);
        uv = fmaf(xin, cwv.w, uv);
        uv = silu_f(uv);
        x0 = x1; x1 = x2; x2 = xin;
        float pre = bv;
#pragma unroll
        for (int j = 0; j < 16; ++j) pre = fmaf(dbcS[r][j], wv[j], pre);
        float dt = softplus_f(pre);
        float du = dt * uv;
        float y = uv * Dv;
#pragma unroll
        for (int s = 0; s < 16; ++s) {
            float dA = expf(dt * Av[s]);
            h[s] = fmaf(dA, h[s], du * dbcS[r][16 + s]);
            y = fmaf(h[s], dbcS[r][32 + s], y);
        }
        float zv = zrow[r * 1024];
        yrow[r * 512] = y * silu_f(zv);
    }
}

// ---------------- decoder convT 2x2 stride2 as GEMM + bias + gelu ----------------
// BM=64, BN=64, BK=16, TM=4, TN=4. AROW: A row-major (m,k); else A is (b,K,HW) k-major.
template <bool AROW>
__global__ __launch_bounds__(256, 4) void convt_gemm(
    const float* __restrict__ A, const float* __restrict__ Wt, const float* __restrict__ bias,
    float* __restrict__ out, int K, int N, int HW, int Wdim, int O) {
    const int tid = threadIdx.x;
    const int n0 = blockIdx.x * 64;
    const int m0 = blockIdx.y * 64;
    __shared__ float As[16][68];
    __shared__ float Bs[16][68];
    const int tx = tid & 15, ty = tid >> 4;
    float acc[4][4] = {};
    for (int k0 = 0; k0 < K; k0 += 16) {
        if constexpr (AROW) {
            int mm = tid >> 2, k4 = tid & 3;
            float4 v = *(const float4*)&A[(size_t)(m0 + mm) * K + k0 + k4 * 4];
            As[k4 * 4 + 0][mm] = v.x;
            As[k4 * 4 + 1][mm] = v.y;
            As[k4 * 4 + 2][mm] = v.z;
            As[k4 * 4 + 3][mm] = v.w;
        } else {
            int b = m0 / HW, hw0 = m0 % HW;
            const float* Ab = A + ((size_t)b * K) * HW + hw0;
#pragma unroll
            for (int idx = tid; idx < 1024; idx += 256) {
                int kk = idx >> 6, mm = idx & 63;
                As[kk][mm] = Ab[(size_t)(k0 + kk) * HW + mm];
            }
        }
        // Wt is k-major (K x N): scalar stage, coalesced global, 2-way LDS banks
#pragma unroll
        for (int idx = tid; idx < 1024; idx += 256) {
            int kk = idx >> 6, nn = idx & 63;
            Bs[kk][nn] = Wt[(size_t)(k0 + kk) * N + n0 + nn];
        }
        __syncthreads();
#pragma unroll
        for (int kk = 0; kk < 16; ++kk) {
            float4 av = *(const float4*)&As[kk][ty * 4];
            float4 bv = *(const float4*)&Bs[kk][tx * 4];
            float a[4] = {av.x, av.y, av.z, av.w};
            float b[4] = {bv.x, bv.y, bv.z, bv.w};
#pragma unroll
            for (int i = 0; i < 4; ++i)
#pragma unroll
                for (int j = 0; j < 4; ++j) acc[i][j] = fmaf(a[i], b[j], acc[i][j]);
        }
        __syncthreads();
    }
    int Hdim = HW / Wdim;
#pragma unroll
    for (int i = 0; i < 4; ++i) {
        int m = m0 + ty * 4 + i;
        int b = m / HW, hw = m % HW;
        int hh = hw / Wdim, ww = hw % Wdim;
#pragma unroll
        for (int j = 0; j < 4; ++j) {
            int n = n0 + tx * 4 + j;
            int o = n >> 2, p = (n >> 1) & 1, q = n & 1;
            out[(((size_t)(b * O + o)) * (2 * Hdim) + 2 * hh + p) * (size_t)(2 * Wdim) + 2 * ww + q] =
                gelu_f(acc[i][j] + bias[o]);
        }
    }
}

// ---------------- final decoder layer: C=32 -> O=1, no gelu ----------------
__global__ void dec4_kernel(const float* __restrict__ d3, const float* __restrict__ w4,
                            const float* __restrict__ b4, float* __restrict__ out) {
    int pix = blockIdx.x * 256 + threadIdx.x;   // 131072
    int b = pix >> 14, hw = pix & 16383;
    int hh = hw >> 7, ww = hw & 127;
    float bias = b4[0];
    float a0 = bias, a1 = bias, a2 = bias, a3 = bias;
    const float* xb = d3 + ((size_t)b * 32) * 16384 + hw;
#pragma unroll 8
    for (int c = 0; c < 32; ++c) {
        float v = xb[(size_t)c * 16384];
        float4 wv = *(const float4*)(w4 + c * 4);
        a0 = fmaf(v, wv.x, a0);
        a1 = fmaf(v, wv.y, a1);
        a2 = fmaf(v, wv.z, a2);
        a3 = fmaf(v, wv.w, a3);
    }
    size_t ob = ((size_t)b * 256 + 2 * hh) * 256 + 2 * ww;
    out[ob] = a0;
    out[ob + 1] = a1;
    out[ob + 256] = a2;
    out[ob + 257] = a3;
}

// ---------------- workspace layout (floats) ----------------
#define H_OFF     ((size_t)0)
#define HN_OFF    ((size_t)524288)
#define TEMB_OFF  ((size_t)1048576)
#define PART_OFF  ((size_t)1050624)
#define XZ_OFF    ((size_t)2099200)
#define PARTX_OFF ((size_t)4196352)
#define YZ_OFF    ((size_t)4589568)
#define HPART_OFF ((size_t)5638144)
#define PPROD_OFF ((size_t)6686720)

extern "C" void kernel_launch(void* const* d_in, const int* in_sizes, int n_in,
                              void* d_out, int out_size, void* d_ws, size_t ws_size,
                              hipStream_t stream) {
    (void)in_sizes; (void)n_in; (void)out_size; (void)ws_size;
    const float* x    = (const float*)d_in[0];
    const int*   t    = (const int*)d_in[1];
    const float* tw1  = (const float*)d_in[2];
    const float* tb1  = (const float*)d_in[3];
    const float* tw2  = (const float*)d_in[4];
    const float* tb2  = (const float*)d_in[5];
    const float* pw   = (const float*)d_in[6];
    const float* pb   = (const float*)d_in[7];
    const float* pos  = (const float*)d_in[8];
    const float* lng  = (const float*)d_in[9];
    const float* lnb  = (const float*)d_in[10];
    const float* ipw  = (const float*)d_in[11];
    const float* cw   = (const float*)d_in[12];
    const float* cb   = (const float*)d_in[13];
    const float* xpw  = (const float*)d_in[14];
    const float* dtw  = (const float*)d_in[15];
    const float* dtb  = (const float*)d_in[16];
    const float* alog = (const float*)d_in[17];
    const float* Dp   = (const float*)d_in[18];
    const float* opw  = (const float*)d_in[19];
    const float* dw1  = (const float*)d_in[20];
    const float* db1  = (const float*)d_in[21];
    const float* dw2  = (const float*)d_in[22];
    const float* db2  = (const float*)d_in[23];
    const float* dw3  = (const float*)d_in[24];
    const float* db3  = (const float*)d_in[25];
    const float* dw4  = (const float*)d_in[26];
    const float* db4  = (const float*)d_in[27];

    float* ws = (float*)d_ws;
    float* H     = ws + H_OFF;
    float* HN    = ws + HN_OFF;
    float* TEMB  = ws + TEMB_OFF;
    float* PART  = ws + PART_OFF;
    float* XZ    = ws + XZ_OFF;
    float* P     = XZ;               // patch matrix alias
    float* PARTX = ws + PARTX_OFF;
    float* YZ    = ws + YZ_OFF;
    float* HPART = ws + HPART_OFF;
    float* PPROD = ws + PPROD_OFF;
    float* D1    = YZ;
    float* D2    = HPART;            // HPART+PPROD contiguous span
    float* D3    = ws;               // over H..XZ span (safe after dec1 consumes H)

    time_emb_kernel<<<NB, 256, 0, stream>>>(t, tw1, tb1, tw2, tb2, TEMB);
    gather_patches<<<1024, 256, 0, stream>>>(x, P);
    // tok partials: M=2048, N=256, K=512 split 2
    gemm_nt<<<dim3(4, 32, 2), 256, 0, stream>>>(P, 512, pw, 512, PART, 256, 256, 524288);
    ln_patch<<<2048, 256, 0, stream>>>(PART, pb, pos, TEMB, lng, lnb, H, HN);

    for (int i = 0; i < 8; ++i) {
        // xz = hn @ in_proj_w[i].T : M=2048, N=1024, K=256
        gemm_nt<<<dim3(16, 32, 1), 256, 0, stream>>>(
            HN, 256, ipw + (size_t)i * 1024 * E, 256, XZ, 1024, 256, 0);
        // dbc partials (conv+silu fused into A staging): K=512 split 4
        xproj_gemm<<<dim3(1, 64, 4), 256, 0, stream>>>(
            XZ, xpw + (size_t)i * 48 * DI, cw + (size_t)i * DI * 4, cb + (size_t)i * DI, PARTX);
        scan_phase1<<<dim3(NC, NB, 2), 256, 0, stream>>>(
            PARTX, XZ, cw + (size_t)i * DI * 4, cb + (size_t)i * DI,
            dtw + (size_t)i * DI * DTR, dtb + (size_t)i * DI,
            alog + (size_t)i * DI * DS, HPART, PPROD);
        scan_phase3<<<dim3(NC, NB, 2), 256, 0, stream>>>(
            PARTX, XZ, cw + (size_t)i * DI * 4, cb + (size_t)i * DI,
            dtw + (size_t)i * DI * DTR, dtb + (size_t)i * DI,
            alog + (size_t)i * DI * DS, Dp + (size_t)i * DI, HPART, PPROD, YZ);
        // out_proj partials: M=2048, N=256, K=512 split 2
        gemm_nt<<<dim3(4, 32, 2), 256, 0, stream>>>(
            YZ, 512, opw + (size_t)i * E * DI, 512, PART, 256, 256, 524288);
        int nl = (i < 7) ? (i + 1) : 0;
        ln_residual<<<2048, 256, 0, stream>>>(
            PART, lng + (size_t)nl * E, lnb + (size_t)nl * E, H, HN, (i < 7) ? 1 : 0);
    }

    // decoder
    convt_gemm<true><<<dim3(8, 32), 256, 0, stream>>>(H, dw1, db1, D1, 256, 512, 256, 16, 128);
    convt_gemm<false><<<dim3(4, 128), 256, 0, stream>>>(D1, dw2, db2, D2, 128, 256, 1024, 32, 64);
    convt_gemm<false><<<dim3(2, 512), 256, 0, stream>>>(D2, dw3, db3, D3, 64, 128, 4096, 64, 32);
    dec4_kernel<<<512, 256, 0, stream>>>(D3, dw4, db4, (float*)d_out);
}

// Round 4
// 945.791 us; speedup vs baseline: 1.2055x; 1.2055x over previous
//
#include <hip/hip_runtime.h>
#include <math.h>

// ---------------- model dims ----------------
#define NB    8      // batch
#define E     256    // embed
#define LTOK  256    // tokens
#define DI    512    // inner dim
#define DS    16     // state dim
#define DTR   16     // dt rank
#define NC    32     // scan chunks
#define CL    8      // chunk length (LTOK/NC)

__device__ __forceinline__ float gelu_f(float x) {
    return 0.5f * x * (1.0f + erff(x * 0.70710678118654752440f));
}
__device__ __forceinline__ float silu_f(float x) {
    return x / (1.0f + expf(-x));
}
__device__ __forceinline__ float softplus_f(float x) {
    return fmaxf(x, 0.0f) + log1pf(expf(-fabsf(x)));
}

// block-wide sum over 256 threads (4 waves). red must be __shared__ float[4].
__device__ __forceinline__ float block_sum256(float x, float* red) {
#pragma unroll
    for (int off = 32; off > 0; off >>= 1) x += __shfl_down(x, off, 64);
    __syncthreads();
    if ((threadIdx.x & 63) == 0) red[threadIdx.x >> 6] = x;
    __syncthreads();
    return red[0] + red[1] + red[2] + red[3];
}

// ---------------- time embedding ----------------
__global__ void time_emb_kernel(const int* __restrict__ t,
                                const float* __restrict__ w1, const float* __restrict__ b1,
                                const float* __restrict__ w2, const float* __restrict__ b2,
                                float* __restrict__ temb) {
    int b = blockIdx.x, e = threadIdx.x;
    __shared__ float hid[E];
    float tf = (float)t[b];
    hid[e] = gelu_f(tf * w1[e] + b1[e]);
    __syncthreads();
    float acc = b2[e];
    for (int k = 0; k < E; ++k) acc = fmaf(hid[k], w2[k * E + e], acc);
    temb[b * E + e] = acc;
}

// ---------------- patch gather: x -> P (2048 x 512) row-major ----------------
__global__ void gather_patches(const float* __restrict__ x, float* __restrict__ P) {
    int idx = blockIdx.x * 256 + threadIdx.x;          // < 262144
    int k4 = idx & 127, m = idx >> 7;
    int b = m >> 8, l = m & 255, hh = l >> 4, ww = l & 15;
    int k = k4 * 4;
    int c = k >> 8, pq = k & 255, p = pq >> 4, q = pq & 15;
    float4 v = *(const float4*)&x[(((size_t)(b * 2 + c) * 256) + hh * 16 + p) * 256 + ww * 16 + q];
    *(float4*)&P[(size_t)m * 512 + k] = v;
}

// ---------------- generic fp32 GEMM (NT) with register prefetch ----------------
// C[m,n] = sum_k A[m,k]*Bw[n,k]. BM=64, BN=64, BK=32, TM=4, TN=4, 256 threads.
// blockIdx.z = K-split slice (per-slice K, kbase = z*K, C += z*zstride).
__global__ __launch_bounds__(256) void gemm_nt(
    const float* __restrict__ A, int lda,
    const float* __restrict__ Bw, int ldb,
    float* __restrict__ C, int ldc, int K, int zstride) {
    const int tid = threadIdx.x;
    const int n0 = blockIdx.x * 64, m0 = blockIdx.y * 64;
    const int kbase = blockIdx.z * K;
    float* Cz = C + (size_t)blockIdx.z * zstride;
    __shared__ float As[32][68];
    __shared__ float Bs[32][68];
    const int tx = tid & 15, ty = tid >> 4;
    const int srow = tid >> 3, sk4 = tid & 7;
    const float* Ap0 = A + (size_t)(m0 + srow) * lda + kbase + sk4 * 4;
    const float* Ap1 = Ap0 + (size_t)32 * lda;
    const float* Bp0 = Bw + (size_t)(n0 + srow) * ldb + kbase + sk4 * 4;
    const float* Bp1 = Bp0 + (size_t)32 * ldb;
    float4 pa0 = *(const float4*)Ap0, pa1 = *(const float4*)Ap1;
    float4 pb0 = *(const float4*)Bp0, pb1 = *(const float4*)Bp1;
    float acc[4][4] = {};
    const int T = K >> 5;
    for (int t = 0;; ++t) {
        As[sk4 * 4 + 0][srow] = pa0.x;  As[sk4 * 4 + 1][srow] = pa0.y;
        As[sk4 * 4 + 2][srow] = pa0.z;  As[sk4 * 4 + 3][srow] = pa0.w;
        As[sk4 * 4 + 0][srow + 32] = pa1.x;  As[sk4 * 4 + 1][srow + 32] = pa1.y;
        As[sk4 * 4 + 2][srow + 32] = pa1.z;  As[sk4 * 4 + 3][srow + 32] = pa1.w;
        Bs[sk4 * 4 + 0][srow] = pb0.x;  Bs[sk4 * 4 + 1][srow] = pb0.y;
        Bs[sk4 * 4 + 2][srow] = pb0.z;  Bs[sk4 * 4 + 3][srow] = pb0.w;
        Bs[sk4 * 4 + 0][srow + 32] = pb1.x;  Bs[sk4 * 4 + 1][srow + 32] = pb1.y;
        Bs[sk4 * 4 + 2][srow + 32] = pb1.z;  Bs[sk4 * 4 + 3][srow + 32] = pb1.w;
        __syncthreads();
        if (t + 1 < T) {
            int off = (t + 1) * 32;
            pa0 = *(const float4*)(Ap0 + off);
            pa1 = *(const float4*)(Ap1 + off);
            pb0 = *(const float4*)(Bp0 + off);
            pb1 = *(const float4*)(Bp1 + off);
        }
#pragma unroll
        for (int kk = 0; kk < 32; ++kk) {
            float4 av = *(const float4*)&As[kk][ty * 4];
            float4 bv = *(const float4*)&Bs[kk][tx * 4];
            float a[4] = {av.x, av.y, av.z, av.w};
            float b[4] = {bv.x, bv.y, bv.z, bv.w};
#pragma unroll
            for (int i = 0; i < 4; ++i)
#pragma unroll
                for (int j = 0; j < 4; ++j) acc[i][j] = fmaf(a[i], b[j], acc[i][j]);
        }
        if (t + 1 >= T) break;
        __syncthreads();
    }
#pragma unroll
    for (int i = 0; i < 4; ++i) {
        int m = m0 + ty * 4 + i;
        *(float4*)&Cz[(size_t)m * ldc + n0 + tx * 4] =
            make_float4(acc[i][0], acc[i][1], acc[i][2], acc[i][3]);
    }
}

// ---------------- LN (patch variant): v = sum of 4 partials + pb+pos+temb -------
__global__ __launch_bounds__(256) void ln_patch(
    const float* __restrict__ part, const float* __restrict__ pb,
    const float* __restrict__ pos, const float* __restrict__ temb,
    const float* __restrict__ g, const float* __restrict__ bta,
    float* __restrict__ h, float* __restrict__ hn) {
    __shared__ float red[4];
    int m = blockIdx.x, e = threadIdx.x;
    int b = m >> 8, l = m & 255;
    size_t o = (size_t)m * 256 + e;
    float v = (part[o] + part[524288 + o]) + (part[1048576 + o] + part[1572864 + o])
            + pb[e] + pos[l * 256 + e] + temb[b * 256 + e];
    h[o] = v;
    float mean = block_sum256(v, red) * (1.0f / 256.0f);
    float dv = v - mean;
    float var = block_sum256(dv * dv, red) * (1.0f / 256.0f);
    float rstd = rsqrtf(var + 1e-5f);
    hn[o] = dv * rstd * g[e] + bta[e];
}

// ---------------- LN (residual variant): v = sum of 4 partials + h ----------------
__global__ __launch_bounds__(256) void ln_residual(
    const float* __restrict__ part,
    const float* __restrict__ g, const float* __restrict__ bta,
    float* __restrict__ h, float* __restrict__ hn, int do_ln) {
    __shared__ float red[4];
    int m = blockIdx.x, e = threadIdx.x;
    size_t o = (size_t)m * 256 + e;
    float v = (part[o] + part[524288 + o]) + (part[1048576 + o] + part[1572864 + o]) + h[o];
    h[o] = v;
    if (!do_ln) return;
    float mean = block_sum256(v, red) * (1.0f / 256.0f);
    float dv = v - mean;
    float var = block_sum256(dv * dv, red) * (1.0f / 256.0f);
    float rstd = rsqrtf(var + 1e-5f);
    hn[o] = dv * rstd * g[e] + bta[e];
}

// ---------------- x_proj GEMM with fused conv+silu A-staging ----------------
// grid (1, 64, 8), 256 threads; per-slice K = 64
__global__ __launch_bounds__(256) void xproj_gemm(
    const float* __restrict__ xz, const float* __restrict__ xpw,
    const float* __restrict__ cw, const float* __restrict__ cb,
    float* __restrict__ partx) {
    const int tid = threadIdx.x;
    const int m0 = blockIdx.y * 32;
    const int kb = blockIdx.z * 64;
    __shared__ float As[16][36];
    __shared__ float Bs[16][52];
    const int tx = tid & 15, ty = tid >> 4;
    float acc[2][3] = {};
    for (int k0 = 0; k0 < 64; k0 += 16) {
#pragma unroll
        for (int idx = tid; idx < 512; idx += 256) {
            int mm = idx >> 4, kk = idx & 15;
            int d = kb + k0 + kk;
            int m = m0 + mm;
            int l = m & 255;
            float4 w4 = *(const float4*)&cw[d * 4];
            float a = cb[d];
            const float* col = xz + (size_t)m * 1024 + d;
            if (l >= 3) {
                a = fmaf(col[-3072], w4.x, a);
                a = fmaf(col[-2048], w4.y, a);
                a = fmaf(col[-1024], w4.z, a);
                a = fmaf(col[0],     w4.w, a);
            } else {
                if (l >= 2) a = fmaf(col[-2048], w4.y, a);
                if (l >= 1) a = fmaf(col[-1024], w4.z, a);
                a = fmaf(col[0], w4.w, a);
            }
            As[kk][mm] = silu_f(a);
        }
#pragma unroll
        for (int idx = tid; idx < 768; idx += 256) {
            int nn = idx >> 4, kk = idx & 15;
            Bs[kk][nn] = xpw[(size_t)nn * 512 + kb + k0 + kk];
        }
        __syncthreads();
#pragma unroll
        for (int kk = 0; kk < 16; ++kk) {
            float a0 = As[kk][ty * 2 + 0];
            float a1 = As[kk][ty * 2 + 1];
            float b0 = Bs[kk][tx * 3 + 0];
            float b1 = Bs[kk][tx * 3 + 1];
            float b2 = Bs[kk][tx * 3 + 2];
            acc[0][0] = fmaf(a0, b0, acc[0][0]);
            acc[0][1] = fmaf(a0, b1, acc[0][1]);
            acc[0][2] = fmaf(a0, b2, acc[0][2]);
            acc[1][0] = fmaf(a1, b0, acc[1][0]);
            acc[1][1] = fmaf(a1, b1, acc[1][1]);
            acc[1][2] = fmaf(a1, b2, acc[1][2]);
        }
        __syncthreads();
    }
    size_t zb = (size_t)blockIdx.z * 98304;
#pragma unroll
    for (int i = 0; i < 2; ++i) {
        int m = m0 + ty * 2 + i;
#pragma unroll
        for (int j = 0; j < 3; ++j)
            partx[zb + (size_t)m * 48 + tx * 3 + j] = acc[i][j];
    }
}

// load dbc tile (CL x 48) = sum of 8 x_proj partials
__device__ __forceinline__ void load_dbc(const float* __restrict__ partx,
                                         int b, int c, float dbcS[CL][48]) {
    for (int idx = threadIdx.x; idx < CL * 48; idx += 256) {
        int r = idx / 48, col = idx % 48;
        size_t o = (size_t)(b * LTOK + c * CL + r) * 48 + col;
        float s = 0.0f;
#pragma unroll
        for (int z = 0; z < 8; ++z) s += partx[(size_t)z * 98304 + o];
        dbcS[r][col] = s;
    }
}

// ---------------- scan phase 1: local chunk scans ----------------
// grid (NC, NB, 2), 256 threads; d = z*256+tid
__global__ __launch_bounds__(256) void scan_phase1(
    const float* __restrict__ partx, const float* __restrict__ xz,
    const float* __restrict__ cw, const float* __restrict__ cb,
    const float* __restrict__ dtw, const float* __restrict__ dtb,
    const float* __restrict__ alog,
    float* __restrict__ hpart, float* __restrict__ pprod) {
    int c = blockIdx.x, b = blockIdx.y;
    int d = blockIdx.z * 256 + threadIdx.x;
    __shared__ float dbcS[CL][48];
    load_dbc(partx, b, c, dbcS);
    float wv[16], Av[16];
#pragma unroll
    for (int s4 = 0; s4 < 16; s4 += 4) {
        float4 t1 = *(const float4*)(dtw + d * 16 + s4);
        wv[s4] = t1.x; wv[s4 + 1] = t1.y; wv[s4 + 2] = t1.z; wv[s4 + 3] = t1.w;
        float4 t2 = *(const float4*)(alog + d * 16 + s4);
        Av[s4] = -expf(t2.x); Av[s4 + 1] = -expf(t2.y); Av[s4 + 2] = -expf(t2.z); Av[s4 + 3] = -expf(t2.w);
    }
    float bv = dtb[d];
    float4 cwv = *(const float4*)&cw[d * 4];
    float cbv = cb[d];
    const float* colp = xz + ((size_t)(b * LTOK + c * CL)) * 1024 + d;
    float x0 = 0.f, x1 = 0.f, x2 = 0.f;
    if (c > 0) { x0 = colp[-3072]; x1 = colp[-2048]; x2 = colp[-1024]; }
    float h[16] = {}, P[16];
#pragma unroll
    for (int s = 0; s < 16; ++s) P[s] = 1.0f;
    __syncthreads();
    for (int r = 0; r < CL; ++r) {
        float xin = colp[r * 1024];
        float uv = cbv;
        uv = fmaf(x0, cwv.x, uv);
        uv = fmaf(x1, cwv.y, uv);
        uv = fmaf(x2, cwv.z, uv);
        uv = fmaf(xin, cwv.w, uv);
        uv = silu_f(uv);
        x0 = x1; x1 = x2; x2 = xin;
        float pre = bv;
#pragma unroll
        for (int j = 0; j < 16; ++j) pre = fmaf(dbcS[r][j], wv[j], pre);
        float dt = softplus_f(pre);
        float du = dt * uv;
#pragma unroll
        for (int s = 0; s < 16; ++s) {
            float dA = expf(dt * Av[s]);
            h[s] = fmaf(dA, h[s], du * dbcS[r][16 + s]);
            P[s] *= dA;
        }
    }
    size_t base = ((size_t)((b * NC + c) * DI) + d) * 16;
#pragma unroll
    for (int s = 0; s < 16; ++s) { hpart[base + s] = h[s]; pprod[base + s] = P[s]; }
}

// ---------------- scan phase 2: combine chunk boundary states ----------------
// grid 256, block 256
__global__ void scan_phase2(const float* __restrict__ hpart, const float* __restrict__ pprod,
                            float* __restrict__ hinit) {
    int idx = blockIdx.x * 256 + threadIdx.x;   // b*8192 + d*16 + s
    int b = idx >> 13, ds = idx & 8191;
    float carry = 0.0f;
    for (int c = 0; c < NC; ++c) {
        size_t a = ((size_t)(b * NC + c)) * (DI * 16) + ds;
        hinit[a] = carry;
        carry = fmaf(pprod[a], carry, hpart[a]);
    }
}

// ---------------- scan phase 3: replay with init state, emit y*silu(z) ----------------
__global__ __launch_bounds__(256) void scan_phase3(
    const float* __restrict__ partx, const float* __restrict__ xz,
    const float* __restrict__ cw, const float* __restrict__ cb,
    const float* __restrict__ dtw, const float* __restrict__ dtb,
    const float* __restrict__ alog, const float* __restrict__ Dpv,
    const float* __restrict__ hinit, float* __restrict__ yz) {
    int c = blockIdx.x, b = blockIdx.y;
    int d = blockIdx.z * 256 + threadIdx.x;
    __shared__ float dbcS[CL][48];
    load_dbc(partx, b, c, dbcS);
    float wv[16], Av[16];
#pragma unroll
    for (int s4 = 0; s4 < 16; s4 += 4) {
        float4 t1 = *(const float4*)(dtw + d * 16 + s4);
        wv[s4] = t1.x; wv[s4 + 1] = t1.y; wv[s4 + 2] = t1.z; wv[s4 + 3] = t1.w;
        float4 t2 = *(const float4*)(alog + d * 16 + s4);
        Av[s4] = -expf(t2.x); Av[s4 + 1] = -expf(t2.y); Av[s4 + 2] = -expf(t2.z); Av[s4 + 3] = -expf(t2.w);
    }
    float bv = dtb[d];
    float Dv = Dpv[d];
    float4 cwv = *(const float4*)&cw[d * 4];
    float cbv = cb[d];
    float h[16];
    size_t base = ((size_t)((b * NC + c) * DI) + d) * 16;
#pragma unroll
    for (int s = 0; s < 16; ++s) h[s] = hinit[base + s];
    const float* colp = xz + ((size_t)(b * LTOK + c * CL)) * 1024 + d;
    const float* zrow = colp + 512;
    float* yrow = yz + ((size_t)(b * LTOK + c * CL)) * 512 + d;
    float x0 = 0.f, x1 = 0.f, x2 = 0.f;
    if (c > 0) { x0 = colp[-3072]; x1 = colp[-2048]; x2 = colp[-1024]; }
    __syncthreads();
    for (int r = 0; r < CL; ++r) {
        float xin = colp[r * 1024];
        float uv = cbv;
        uv = fmaf(x0, cwv.x, uv);
        uv = fmaf(x1, cwv.y, uv);
        uv = fmaf(x2, cwv.z, uv);
        uv = fmaf(xin, cwv.w, uv);
        uv = silu_f(uv);
        x0 = x1; x1 = x2; x2 = xin;
        float pre = bv;
#pragma unroll
        for (int j = 0; j < 16; ++j) pre = fmaf(dbcS[r][j], wv[j], pre);
        float dt = softplus_f(pre);
        float du = dt * uv;
        float y = uv * Dv;
#pragma unroll
        for (int s = 0; s < 16; ++s) {
            float dA = expf(dt * Av[s]);
            h[s] = fmaf(dA, h[s], du * dbcS[r][16 + s]);
            y = fmaf(h[s], dbcS[r][32 + s], y);
        }
        float zv = zrow[r * 1024];
        yrow[r * 512] = y * silu_f(zv);
    }
}

// ---------------- decoder convT 2x2 stride2 as GEMM + bias + gelu (prefetch) --------
// BM template (32 or 64), BN=64, BK=32, TM=BM/16, TN=4, 256 threads.
// AROW: A row-major (m,k); else A is (b, K, HW) k-major.
template <int BM, bool AROW>
__global__ __launch_bounds__(256) void convt_gemm(
    const float* __restrict__ A, const float* __restrict__ Wt, const float* __restrict__ bias,
    float* __restrict__ out, int K, int N, int HW, int Wdim, int O) {
    constexpr int TM = BM / 16;
    const int tid = threadIdx.x;
    const int n0 = blockIdx.x * 64;
    const int m0 = blockIdx.y * BM;
    __shared__ float As[32][BM + 4];
    __shared__ float Bs[32][68];
    const int tx = tid & 15, ty = tid >> 4;
    float acc[TM][4] = {};
    const int T = K >> 5;
    // prefetch state
    float4 pa0, pa1;                 // AROW path
    float pra[8];                    // k-major path
    float prb[8];                    // Wt rows
    const int srow = tid >> 3, sk4 = tid & 7;
    const float* Ap0; const float* Ap1; const float* Ab;
    if constexpr (AROW) {
        Ap0 = A + (size_t)(m0 + srow) * K + sk4 * 4;
        Ap1 = Ap0 + (size_t)32 * K;
        pa0 = *(const float4*)Ap0;
        if constexpr (BM == 64) pa1 = *(const float4*)Ap1;
    } else {
        int bb = m0 / HW, hw0 = m0 % HW;
        Ab = A + ((size_t)bb * K) * HW + hw0;
#pragma unroll
        for (int f = 0; f < BM / 8; ++f)
            pra[f] = Ab[(size_t)((tid >> 6) + 4 * f) * HW + (tid & 63)];
    }
    {
#pragma unroll
        for (int f = 0; f < 8; ++f)
            prb[f] = Wt[(size_t)((tid >> 6) + 4 * f) * N + n0 + (tid & 63)];
    }
    for (int t = 0;; ++t) {
        if constexpr (AROW) {
            As[sk4 * 4 + 0][srow] = pa0.x;  As[sk4 * 4 + 1][srow] = pa0.y;
            As[sk4 * 4 + 2][srow] = pa0.z;  As[sk4 * 4 + 3][srow] = pa0.w;
            if constexpr (BM == 64) {
                As[sk4 * 4 + 0][srow + 32] = pa1.x;  As[sk4 * 4 + 1][srow + 32] = pa1.y;
                As[sk4 * 4 + 2][srow + 32] = pa1.z;  As[sk4 * 4 + 3][srow + 32] = pa1.w;
            }
        } else {
#pragma unroll
            for (int f = 0; f < BM / 8; ++f) {
                int kk = (tid >> 6) + 4 * f;
                if constexpr (BM == 64) As[kk][tid & 63] = pra[f];
                else As[kk >> 1][((kk & 1) << 5) | (tid & 31)] = 0;  // unused
            }
        }
#pragma unroll
        for (int f = 0; f < 8; ++f)
            Bs[(tid >> 6) + 4 * f][tid & 63] = prb[f];
        __syncthreads();
        if (t + 1 < T) {
            int off = (t + 1) * 32;
            if constexpr (AROW) {
                pa0 = *(const float4*)(Ap0 + off);
                if constexpr (BM == 64) pa1 = *(const float4*)(Ap1 + off);
            } else {
#pragma unroll
                for (int f = 0; f < BM / 8; ++f)
                    pra[f] = Ab[(size_t)(off + (tid >> 6) + 4 * f) * HW + (tid & 63)];
            }
#pragma unroll
            for (int f = 0; f < 8; ++f)
                prb[f] = Wt[(size_t)(off + (tid >> 6) + 4 * f) * N + n0 + (tid & 63)];
        }
#pragma unroll
        for (int kk = 0; kk < 32; ++kk) {
            float a[TM];
#pragma unroll
            for (int i = 0; i < TM; ++i) a[i] = As[kk][ty * TM + i];
            float4 bv = *(const float4*)&Bs[kk][tx * 4];
            float b[4] = {bv.x, bv.y, bv.z, bv.w};
#pragma unroll
            for (int i = 0; i < TM; ++i)
#pragma unroll
                for (int j = 0; j < 4; ++j) acc[i][j] = fmaf(a[i], b[j], acc[i][j]);
        }
        if (t + 1 >= T) break;
        __syncthreads();
    }
    int Hdim = HW / Wdim;
#pragma unroll
    for (int i = 0; i < TM; ++i) {
        int m = m0 + ty * TM + i;
        int b = m / HW, hw = m % HW;
        int hh = hw / Wdim, ww = hw % Wdim;
#pragma unroll
        for (int j = 0; j < 4; ++j) {
            int n = n0 + tx * 4 + j;
            int o = n >> 2, p = (n >> 1) & 1, q = n & 1;
            out[(((size_t)(b * O + o)) * (2 * Hdim) + 2 * hh + p) * (size_t)(2 * Wdim) + 2 * ww + q] =
                gelu_f(acc[i][j] + bias[o]);
        }
    }
}

// ---------------- final decoder layer: C=32 -> O=1, no gelu ----------------
__global__ void dec4_kernel(const float* __restrict__ d3, const float* __restrict__ w4,
                            const float* __restrict__ b4, float* __restrict__ out) {
    int pix = blockIdx.x * 256 + threadIdx.x;   // 131072
    int b = pix >> 14, hw = pix & 16383;
    int hh = hw >> 7, ww = hw & 127;
    float bias = b4[0];
    float a0 = bias, a1 = bias, a2 = bias, a3 = bias;
    const float* xb = d3 + ((size_t)b * 32) * 16384 + hw;
#pragma unroll 8
    for (int c = 0; c < 32; ++c) {
        float v = xb[(size_t)c * 16384];
        float4 wv = *(const float4*)(w4 + c * 4);
        a0 = fmaf(v, wv.x, a0);
        a1 = fmaf(v, wv.y, a1);
        a2 = fmaf(v, wv.z, a2);
        a3 = fmaf(v, wv.w, a3);
    }
    size_t ob = ((size_t)b * 256 + 2 * hh) * 256 + 2 * ww;
    out[ob] = a0;
    out[ob + 1] = a1;
    out[ob + 256] = a2;
    out[ob + 257] = a3;
}

// ---------------- workspace layout (floats) ----------------
#define H_OFF     ((size_t)0)
#define HN_OFF    ((size_t)524288)
#define TEMB_OFF  ((size_t)1048576)
#define PART_OFF  ((size_t)1050624)   // 4 x 524288
#define XZ_OFF    ((size_t)3147776)   // 2097152
#define PARTX_OFF ((size_t)5244928)   // 8 x 98304
#define YZ_OFF    ((size_t)6031360)   // 1048576
#define HPART_OFF ((size_t)7079936)   // 2097152
#define PPROD_OFF ((size_t)9177088)   // 2097152
#define HINIT_OFF ((size_t)11274240)  // 2097152

extern "C" void kernel_launch(void* const* d_in, const int* in_sizes, int n_in,
                              void* d_out, int out_size, void* d_ws, size_t ws_size,
                              hipStream_t stream) {
    (void)in_sizes; (void)n_in; (void)out_size; (void)ws_size;
    const float* x    = (const float*)d_in[0];
    const int*   t    = (const int*)d_in[1];
    const float* tw1  = (const float*)d_in[2];
    const float* tb1  = (const float*)d_in[3];
    const float* tw2  = (const float*)d_in[4];
    const float* tb2  = (const float*)d_in[5];
    const float* pw   = (const float*)d_in[6];
    const float* pb   = (const float*)d_in[7];
    const float* pos  = (const float*)d_in[8];
    const float* lng  = (const float*)d_in[9];
    const float* lnb  = (const float*)d_in[10];
    const float* ipw  = (const float*)d_in[11];
    const float* cw   = (const float*)d_in[12];
    const float* cb   = (const float*)d_in[13];
    const float* xpw  = (const float*)d_in[14];
    const float* dtw  = (const float*)d_in[15];
    const float* dtb  = (const float*)d_in[16];
    const float* alog = (const float*)d_in[17];
    const float* Dp   = (const float*)d_in[18];
    const float* opw  = (const float*)d_in[19];
    const float* dw1  = (const float*)d_in[20];
    const float* db1  = (const float*)d_in[21];
    const float* dw2  = (const float*)d_in[22];
    const float* db2  = (const float*)d_in[23];
    const float* dw3  = (const float*)d_in[24];
    const float* db3  = (const float*)d_in[25];
    const float* dw4  = (const float*)d_in[26];
    const float* db4  = (const float*)d_in[27];

    float* ws = (float*)d_ws;
    float* H     = ws + H_OFF;
    float* HN    = ws + HN_OFF;
    float* TEMB  = ws + TEMB_OFF;
    float* PART  = ws + PART_OFF;
    float* XZ    = ws + XZ_OFF;
    float* P     = XZ;               // patch matrix alias
    float* PARTX = ws + PARTX_OFF;
    float* YZ    = ws + YZ_OFF;
    float* HPART = ws + HPART_OFF;
    float* PPROD = ws + PPROD_OFF;
    float* HINIT = ws + HINIT_OFF;
    float* D1    = YZ;               // 1M floats
    float* D2    = HPART;            // 2M floats
    float* D3    = ws;               // 4M floats over dead H..XZ-low span

    time_emb_kernel<<<NB, 256, 0, stream>>>(t, tw1, tb1, tw2, tb2, TEMB);
    gather_patches<<<1024, 256, 0, stream>>>(x, P);
    // tok partials: M=2048, N=256, K=512 split 4
    gemm_nt<<<dim3(4, 32, 4), 256, 0, stream>>>(P, 512, pw, 512, PART, 256, 128, 524288);
    ln_patch<<<2048, 256, 0, stream>>>(PART, pb, pos, TEMB, lng, lnb, H, HN);

    for (int i = 0; i < 8; ++i) {
        // xz = hn @ in_proj_w[i].T : M=2048, N=1024, K=256
        gemm_nt<<<dim3(16, 32, 1), 256, 0, stream>>>(
            HN, 256, ipw + (size_t)i * 1024 * E, 256, XZ, 1024, 256, 0);
        // dbc partials (conv+silu fused into A staging): K=512 split 8
        xproj_gemm<<<dim3(1, 64, 8), 256, 0, stream>>>(
            XZ, xpw + (size_t)i * 48 * DI, cw + (size_t)i * DI * 4, cb + (size_t)i * DI, PARTX);
        scan_phase1<<<dim3(NC, NB, 2), 256, 0, stream>>>(
            PARTX, XZ, cw + (size_t)i * DI * 4, cb + (size_t)i * DI,
            dtw + (size_t)i * DI * DTR, dtb + (size_t)i * DI,
            alog + (size_t)i * DI * DS, HPART, PPROD);
        scan_phase2<<<256, 256, 0, stream>>>(HPART, PPROD, HINIT);
        scan_phase3<<<dim3(NC, NB, 2), 256, 0, stream>>>(
            PARTX, XZ, cw + (size_t)i * DI * 4, cb + (size_t)i * DI,
            dtw + (size_t)i * DI * DTR, dtb + (size_t)i * DI,
            alog + (size_t)i * DI * DS, Dp + (size_t)i * DI, HINIT, YZ);
        // out_proj partials: M=2048, N=256, K=512 split 4
        gemm_nt<<<dim3(4, 32, 4), 256, 0, stream>>>(
            YZ, 512, opw + (size_t)i * E * DI, 512, PART, 256, 128, 524288);
        int nl = (i < 7) ? (i + 1) : 0;
        ln_residual<<<2048, 256, 0, stream>>>(
            PART, lng + (size_t)nl * E, lnb + (size_t)nl * E, H, HN, (i < 7) ? 1 : 0);
    }

    // decoder
    convt_gemm<32, true><<<dim3(8, 64), 256, 0, stream>>>(H, dw1, db1, D1, 256, 512, 256, 16, 128);
    convt_gemm<64, false><<<dim3(4, 128), 256, 0, stream>>>(D1, dw2, db2, D2, 128, 256, 1024, 32, 64);
    convt_gemm<64, false><<<dim3(2, 512), 256, 0, stream>>>(D2, dw3, db3, D3, 64, 128, 4096, 64, 32);
    dec4_kernel<<<512, 256, 0, stream>>>(D3, dw4, db4, (float*)d_out);
}